// Round 7
// baseline (342.146 us; speedup 1.0000x reference)
//
#include <hip/hip_runtime.h>
#include <math.h>

// x: (64,512,256) f32 -> 32768 tokens x 256 dims. codebook: (8192,256) f32.
#define N_TOK 32768
#define DDIM  256
#define KCB   8192
#define SLICES 4
#define KS     (KCB / SLICES)    // 2048 codes per slice
#define TCODES 64                // codes per LDS tile
#define NSTEP  (KS / TCODES)     // 32 tiles per slice
#define TOKB   256               // tokens per block (64/wave, 4 waves)
#define NTB    (N_TOK / TOKB)    // 128 token-blocks
#define NBLKS  (NTB * SLICES)    // 512 blocks == full co-residency (2/CU)
#define MARGIN 1.0f              // acc-scale gap guaranteeing exact winner

typedef _Float16 half_t;
typedef half_t half8 __attribute__((ext_vector_type(8)));
typedef half_t half4 __attribute__((ext_vector_type(4)));
typedef float  f32x4 __attribute__((ext_vector_type(4)));
typedef float  f32x2 __attribute__((ext_vector_type(2)));

#define GLOBAL_AS __attribute__((address_space(1)))
#define LDS_AS    __attribute__((address_space(3)))

// load 8 consecutive f32, convert to 8 f16 (prologue only)
__device__ __forceinline__ half8 ldcvt8(const float* __restrict__ p) {
    f32x4 a = *(const f32x4*)p;
    f32x4 b = *(const f32x4*)(p + 4);
    half8 h;
    h[0]=(half_t)a[0]; h[1]=(half_t)a[1]; h[2]=(half_t)a[2]; h[3]=(half_t)a[3];
    h[4]=(half_t)b[0]; h[5]=(half_t)b[1]; h[6]=(half_t)b[2]; h[7]=(half_t)b[3];
    return h;
}

// pack: f32 key with low 13 mantissa bits replaced by code id (sortable)
__device__ __forceinline__ float packkey(float a, unsigned code) {
    return __uint_as_float((__float_as_uint(a) & 0xFFFFE000u) | code);
}

// ---------------------------------------------------------------------------
// Single fused kernel, 512 blocks x 256 threads (= exact co-residency at
// 74 KB LDS: 2 blocks/CU x 256 CU, so global spin-barriers cannot deadlock).
//   phase P: each block converts 16 codebook rows f32->f16 + norms,
//            then spin-barrier on prep_tk (memset-reset each replay).
//   phase A: passA core (R0 config, VERBATIM -- best measured 136.4us).
//   phase F: ticket per token-block bx: all 4 slice-blocks spin until
//            tickets[bx]==4 (R6's validated release/acquire protocol),
//            then EACH finalizes 64 tokens (R6 did 256 on 1 block -> 80us
//            tail at 1/4 machine utilization; this is the 4x fix).
//   phase L: last of 512 blocks reduces the loss partials.
__global__ __launch_bounds__(256, 2)
void vq_main(const float* __restrict__ x, const float* __restrict__ cb,
             half_t* __restrict__ cb16, float* __restrict__ cnorm,
             float* __restrict__ cand, float* __restrict__ out,
             float* __restrict__ partials, unsigned* __restrict__ tickets,
             unsigned* __restrict__ ticket2, unsigned* __restrict__ prep_tk) {

    __shared__ __align__(16) half_t buf[2][TCODES * 256];   // 2 x 32 KB
    __shared__ __align__(16) float  cn_lds[KS];             // 8 KB
    __shared__ float redf[4];
    __shared__ int   flag;

    const int tid  = threadIdx.x;
    const int w    = tid >> 6;
    const int lane = tid & 63;
    const int quad = lane >> 4;
    const int mcol = lane & 15;
    const int bx   = blockIdx.x;               // token-block 0..127
    const int by   = blockIdx.y;               // slice 0..3
    const int tokBase   = bx * TOKB + w * 64;  // wave's 64 tokens
    const int codeBase0 = by * KS;

    // ================= phase P: prep 16 codebook rows, spin-barrier =========
    {
        const int g = by * NTB + bx;           // 0..511
        #pragma unroll
        for (int o = 0; o < 4; o++) {
            int code = g * 16 + o * 4 + w;
            f32x4 v = *(const f32x4*)(cb + (size_t)code * DDIM + lane * 4);
            half4 h; h[0]=(half_t)v[0]; h[1]=(half_t)v[1]; h[2]=(half_t)v[2]; h[3]=(half_t)v[3];
            *(half4*)(cb16 + (size_t)code * DDIM + lane * 4) = h;
            float s = v[0]*v[0] + v[1]*v[1] + v[2]*v[2] + v[3]*v[3];
            #pragma unroll
            for (int off = 32; off > 0; off >>= 1) s += __shfl_down(s, off);
            if (lane == 0) cnorm[code] = s;
        }
    }
    __syncthreads();                 // drains this block's stores (vmcnt 0)
    if (tid == 0) {
        __threadfence();             // release to device scope
        atomicAdd(prep_tk, 1u);
        while (__hip_atomic_load(prep_tk, __ATOMIC_RELAXED,
                                 __HIP_MEMORY_SCOPE_AGENT) < (unsigned)NBLKS)
            __builtin_amdgcn_s_sleep(1);
    }
    __syncthreads();
    __threadfence();                 // acquire

    // ================= phase A: passA core (R0, verbatim) ===================
    // ---- A fragments: A[m=mcol][k=quad*8+j], full D=256 in regs (128 regs)
    half8 afrag[4][8];
    #pragma unroll
    for (int rt = 0; rt < 4; rt++) {
        const float* xr = x + (size_t)(tokBase + rt * 16 + mcol) * DDIM + quad * 8;
        #pragma unroll
        for (int dk = 0; dk < 8; dk++)
            afrag[rt][dk] = ldcvt8(xr + dk * 32);
    }

    // ---- B-read LDS offsets (halves): row = mcol, chunk = (dk*4+quad)^(mcol&7)
    int boff[8];
    #pragma unroll
    for (int dk = 0; dk < 8; dk++)
        boff[dk] = mcol * 256 + (((dk * 4 + quad) ^ (mcol & 7)) * 8);

    // packed top-2 keys (max semantics) per owned token [rt][r]
    float k0[4][4], k1[4][4];
    #pragma unroll
    for (int rt = 0; rt < 4; rt++)
        #pragma unroll
        for (int r = 0; r < 4; r++) { k0[rt][r] = -INFINITY; k1[rt][r] = -INFINITY; }

    // stage 32 KB tile nt into buffer b (async, swizzled to match read side)
    const char* cbbase = (const char*)(cb16 + (size_t)codeBase0 * DDIM);
    #define STAGE(nt, b)                                                        \
        {                                                                       \
            const char* srcb = cbbase + (size_t)(nt) * (TCODES * 512);          \
            _Pragma("unroll")                                                   \
            for (int o = 0; o < 8; o++) {                                       \
                int L = o * 256 + tid;                                          \
                int r = L >> 5, c = (L & 31) ^ (r & 7);                         \
                __builtin_amdgcn_global_load_lds(                               \
                    (const GLOBAL_AS void*)(srcb + r * 512 + c * 16),           \
                    (LDS_AS void*)&buf[b][(o * 256 + w * 64) * 8], 16, 0, 0);   \
            }                                                                   \
        }

    // one-time cnorm slice -> LDS (drains with prologue)
    {
        const float* cnsrc = cnorm + codeBase0;
        #pragma unroll
        for (int o = 0; o < 8; o++)
            __builtin_amdgcn_global_load_lds(
                (const GLOBAL_AS void*)(cnsrc + o * 256 + w * 64 + lane),
                (LDS_AS void*)&cn_lds[o * 256 + w * 64], 4, 0, 0);
    }
    STAGE(0, 0)
    asm volatile("s_waitcnt vmcnt(0)" ::: "memory");   // prologue drain (only one)
    __builtin_amdgcn_s_barrier();

    for (int nt = 0; nt < NSTEP; nt++) {
        if (nt + 1 < NSTEP) {
            STAGE(nt + 1, (nt + 1) & 1)
            asm volatile("s_waitcnt vmcnt(8)" ::: "memory");
        } else {
            asm volatile("s_waitcnt vmcnt(0)" ::: "memory");
        }
        __builtin_amdgcn_s_barrier();       // tile nt resident for all waves

        const half_t* cur = buf[nt & 1];
        const int codeBase = codeBase0 + nt * TCODES;

        #pragma unroll
        for (int p = 0; p < 2; p++) {                  // two 32-code passes
            const float mc0 = -0.5f * cn_lds[nt * TCODES + p * 32 + mcol];
            const float mc1 = -0.5f * cn_lds[nt * TCODES + p * 32 + 16 + mcol];
            f32x4 acc[2][4];
            #pragma unroll
            for (int rt = 0; rt < 4; rt++) {
                acc[0][rt][0]=mc0; acc[0][rt][1]=mc0; acc[0][rt][2]=mc0; acc[0][rt][3]=mc0;
                acc[1][rt][0]=mc1; acc[1][rt][1]=mc1; acc[1][rt][2]=mc1; acc[1][rt][3]=mc1;
            }
            const half_t* crow0 = cur + (p * 32) * 256;
            const half_t* crow1 = cur + (p * 32 + 16) * 256;
            __builtin_amdgcn_s_setprio(1);
            #pragma unroll
            for (int dk = 0; dk < 8; dk++) {
                half8 bf0 = *(const half8*)(crow0 + boff[dk]);
                half8 bf1 = *(const half8*)(crow1 + boff[dk]);
                #pragma unroll
                for (int rt = 0; rt < 4; rt++) {
                    acc[0][rt] = __builtin_amdgcn_mfma_f32_16x16x32_f16(afrag[rt][dk], bf0, acc[0][rt], 0, 0, 0);
                    acc[1][rt] = __builtin_amdgcn_mfma_f32_16x16x32_f16(afrag[rt][dk], bf1, acc[1][rt], 0, 0, 0);
                }
            }
            __builtin_amdgcn_s_setprio(0);
            // C layout: col = lane&15 (code), row = quad*4 + r (token).
            const unsigned code0 = (unsigned)(codeBase + p * 32 + mcol);
            const unsigned code1 = code0 + 16;
            #pragma unroll
            for (int rt = 0; rt < 4; rt++)
                #pragma unroll
                for (int r = 0; r < 4; r++) {
                    float a = packkey(acc[0][rt][r], code0);
                    float b = packkey(acc[1][rt][r], code1);
                    k1[rt][r] = fmaxf(k1[rt][r], __builtin_amdgcn_fmed3f(k0[rt][r], a, b));
                    k0[rt][r] = fmaxf(fmaxf(k0[rt][r], a), b);
                }
        }
        __builtin_amdgcn_s_barrier();       // reads done -> STAGE may overwrite
    }

    // ---- merge top-2 (max) across the 16 class lanes; lane mcol==0 writes.
    #pragma unroll
    for (int s = 1; s < 16; s <<= 1) {
        #pragma unroll
        for (int rt = 0; rt < 4; rt++)
            #pragma unroll
            for (int r = 0; r < 4; r++) {
                float o0 = __shfl_xor(k0[rt][r], s, 64);
                float o1 = __shfl_xor(k1[rt][r], s, 64);
                float n1 = fmaxf(fminf(k0[rt][r], o0), fmaxf(k1[rt][r], o1));
                k0[rt][r] = fmaxf(k0[rt][r], o0);
                k1[rt][r] = n1;
            }
    }
    if (mcol == 0) {
        #pragma unroll
        for (int rt = 0; rt < 4; rt++)
            #pragma unroll
            for (int r = 0; r < 4; r++) {
                int token = tokBase + rt * 16 + quad * 4 + r;
                f32x2 kk; kk[0] = k0[rt][r]; kk[1] = k1[rt][r];
                *(f32x2*)&cand[(size_t)token * (SLICES * 2) + by * 2] = kk;
            }
    }

    // ==== phase F: spin until all 4 slices of bx wrote cand, then each =====
    // ==== slice-block finalizes its own 64-token quarter (4x R6's par.) ====
    __syncthreads();                 // cand stores drained to L2
    if (tid == 0) {
        __threadfence();             // release
        atomicAdd(&tickets[bx], 1u);
        while (__hip_atomic_load(&tickets[bx], __ATOMIC_RELAXED,
                                 __HIP_MEMORY_SCOPE_AGENT) < (unsigned)SLICES)
            __builtin_amdgcn_s_sleep(1);
    }
    __syncthreads();
    __threadfence();                 // acquire

    float lacc = 0.0f;
    for (int i = 0; i < 16; i++) {
        const int token = bx * TOKB + by * 64 + w * 16 + i;
        const float* xrow = x + (size_t)token * DDIM;

        f32x4 ka = *(const f32x4*)(cand + (size_t)token * 8);
        f32x4 kb = *(const f32x4*)(cand + (size_t)token * 8 + 4);
        float v0 = ka[0], v1 = ka[1], v2 = ka[2], v3 = ka[3];
        float v4 = kb[0], v5 = kb[1], v6 = kb[2], v7 = kb[3];
        float t0 = -INFINITY, t1 = -INFINITY;
        #define TOP2(vv) { float m = fminf(t0, vv); t0 = fmaxf(t0, vv); t1 = fmaxf(t1, m); }
        TOP2(v0) TOP2(v1) TOP2(v2) TOP2(v3) TOP2(v4) TOP2(v5) TOP2(v6) TOP2(v7)
        #undef TOP2
        int bidx = (int)(__float_as_uint(t0) & 0x1FFFu);

        if (!(t0 - t1 > MARGIN)) {      // wave-uniform branch
            const int j = lane >> 3, sub = lane & 7;
            float vj = cand[(size_t)token * 8 + j];   // per-group scalar
            int   cj = (int)(__float_as_uint(vj) & 0x1FFFu);
            float bd = INFINITY;
            int   bi = cj;
            if (vj >= t0 - MARGIN) {    // uniform within each 8-lane group
                const float* crow = cb + (size_t)cj * DDIM;
                float p = 0.0f;
                #pragma unroll
                for (int c = 0; c < 8; c++) {
                    f32x4 xa = *(const f32x4*)(xrow + c * 32 + sub * 4);
                    f32x4 ca = *(const f32x4*)(crow + c * 32 + sub * 4);
                    p += xa[0]*ca[0] + xa[1]*ca[1] + xa[2]*ca[2] + xa[3]*ca[3];
                }
                p += __shfl_xor(p, 1, 64);
                p += __shfl_xor(p, 2, 64);
                p += __shfl_xor(p, 4, 64);
                bd = cnorm[cj] - 2.0f * p;
            }
            #pragma unroll
            for (int s = 8; s < 64; s <<= 1) {   // tie-break: lower index
                float od = __shfl_xor(bd, s, 64);
                int   oi = __shfl_xor(bi, s, 64);
                if (od < bd || (od == bd && oi < bi)) { bd = od; bi = oi; }
            }
            bidx = bi;
        }

        f32x4 cv = *(const f32x4*)(cb + (size_t)bidx * DDIM + lane * 4);
        f32x4 xv = *(const f32x4*)(xrow + lane * 4);
        *(f32x4*)(out + (size_t)token * DDIM + lane * 4) = cv;
        float d0 = cv[0]-xv[0], d1 = cv[1]-xv[1], d2 = cv[2]-xv[2], d3 = cv[3]-xv[3];
        lacc += d0*d0 + d1*d1 + d2*d2 + d3*d3;
    }
    #pragma unroll
    for (int s = 1; s < 64; s <<= 1) lacc += __shfl_xor(lacc, s, 64);
    if (lane == 0) redf[w] = lacc;
    __syncthreads();
    if (tid == 0) partials[by * NTB + bx] = redf[0] + redf[1] + redf[2] + redf[3];

    // ==== phase L: last of the 512 blocks reduces the loss ==================
    __syncthreads();
    if (tid == 0) {
        __threadfence();
        flag = (atomicAdd(ticket2, 1u) == (unsigned)(NBLKS - 1));
    }
    __syncthreads();
    if (!flag) return;
    __threadfence();
    float s = partials[tid] + partials[tid + 256];
    #pragma unroll
    for (int st = 1; st < 64; st <<= 1) s += __shfl_xor(s, st, 64);
    if (lane == 0) redf[w] = s;
    __syncthreads();
    if (tid == 0)
        out[(size_t)N_TOK * DDIM] = (redf[0] + redf[1] + redf[2] + redf[3]) *
                                    (0.25f / (float)((size_t)N_TOK * DDIM));
}

// ---------------------------------------------------------------------------
extern "C" void kernel_launch(void* const* d_in, const int* in_sizes, int n_in,
                              void* d_out, int out_size, void* d_ws, size_t ws_size,
                              hipStream_t stream) {
    const float* x  = (const float*)d_in[0];
    const float* cb = (const float*)d_in[1];
    float* out = (float*)d_out;

    // ws: cb16 (4 MB f16) | cnorm[8192] | cand[32768*8] | partials[512] |
    //     tickets[128] | ticket2[1] | prep_tk[1]
    half_t*   cb16     = (half_t*)d_ws;
    float*    cnorm    = (float*)(cb16 + (size_t)KCB * DDIM);
    float*    cand     = cnorm + KCB;
    float*    partials = cand + (size_t)N_TOK * 8;
    unsigned* tickets  = (unsigned*)(partials + NBLKS);
    unsigned* ticket2  = tickets + NTB;
    unsigned* prep_tk  = ticket2 + 1;

    hipMemsetAsync(tickets, 0, (NTB + 2) * sizeof(unsigned), stream);
    dim3 gA(NTB, SLICES);
    vq_main<<<gA, 256, 0, stream>>>(x, cb, cb16, cnorm, cand, out,
                                    partials, tickets, ticket2, prep_tk);
}

// Round 8
// 223.996 us; speedup vs baseline: 1.5275x; 1.5275x over previous
//
#include <hip/hip_runtime.h>
#include <math.h>

// x: (64,512,256) f32 -> 32768 tokens x 256 dims. codebook: (8192,256) f32.
#define N_TOK 32768
#define DDIM  256
#define KCB   8192
#define SLICES 4
#define KS     (KCB / SLICES)    // 2048 codes per slice
#define TCODES 32                // codes per LDS tile (3-buffer pipeline)
#define NSTEP  (KS / TCODES)     // 64 tiles per slice
#define NBUF   3                 // triple buffer -> prefetch depth 2
#define MARGIN 1.0f              // acc-scale gap guaranteeing exact winner
#define NFBLK  (N_TOK / 4)       // finalize blocks (1 token/wave, 4 waves)

typedef _Float16 half_t;
typedef half_t half8 __attribute__((ext_vector_type(8)));
typedef half_t half4 __attribute__((ext_vector_type(4)));
typedef float  f32x4 __attribute__((ext_vector_type(4)));
typedef float  f32x2 __attribute__((ext_vector_type(2)));

#define GLOBAL_AS __attribute__((address_space(1)))
#define LDS_AS    __attribute__((address_space(3)))

// ---------------------------------------------------------------------------
// P0: codebook f32 -> f16 copy + fp32 row norms.  (R0 verbatim)
__global__ __launch_bounds__(64) void prep_cb(const float* __restrict__ cb,
                                              half_t* __restrict__ cb16,
                                              float* __restrict__ cnorm) {
    int code = blockIdx.x;
    int lane = threadIdx.x;
    f32x4 v = *(const f32x4*)(cb + (size_t)code * DDIM + lane * 4);
    half4 h; h[0]=(half_t)v[0]; h[1]=(half_t)v[1]; h[2]=(half_t)v[2]; h[3]=(half_t)v[3];
    *(half4*)(cb16 + (size_t)code * DDIM + lane * 4) = h;
    float s = v[0]*v[0] + v[1]*v[1] + v[2]*v[2] + v[3]*v[3];
    #pragma unroll
    for (int off = 32; off > 0; off >>= 1) s += __shfl_down(s, off);
    if (lane == 0) cnorm[code] = s;
}

// load 8 consecutive f32, convert to 8 f16 (prologue only)
__device__ __forceinline__ half8 ldcvt8(const float* __restrict__ p) {
    f32x4 a = *(const f32x4*)p;
    f32x4 b = *(const f32x4*)(p + 4);
    half8 h;
    h[0]=(half_t)a[0]; h[1]=(half_t)a[1]; h[2]=(half_t)a[2]; h[3]=(half_t)a[3];
    h[4]=(half_t)b[0]; h[5]=(half_t)b[1]; h[6]=(half_t)b[2]; h[7]=(half_t)b[3];
    return h;
}

// pack: f32 key with low 13 mantissa bits replaced by code id (sortable)
__device__ __forceinline__ float packkey(float a, unsigned code) {
    return __uint_as_float((__float_as_uint(a) & 0xFFFFE000u) | code);
}

// ---------------------------------------------------------------------------
// Pass A: 256 threads (4 waves), 256 tokens/block (64/wave), one 2048-code
// K-slice.  R0 structure EXCEPT: 3 x 16KB tile buffers with prefetch DEPTH 2
// -- iteration t issues STAGE(t+2) and waits vmcnt(8), so the tile being
// consumed (t) had TWO compute windows (~620cy) for its loads to land; the
// barrier-adjacent wait is genuinely zero (R1's depth-1 counted-vmcnt still
// waited on a one-window-old tile; R3 quantified depth-1 latency exposure).
// Race-free: STAGE(t+2) overwrites buf[(t+2)%3], last read at iter t-1,
// and B2 of t-1 precedes any wave's iter-t STAGE.
// LDS: 3x16KB + 8KB cnorm = 56KB -> 2 blocks/CU (as R0).
__global__ __launch_bounds__(256, 2)
void passA(const float* __restrict__ x, const half_t* __restrict__ cb16,
           const float* __restrict__ cnorm, float* __restrict__ cand) {

    __shared__ __align__(16) half_t buf[NBUF][TCODES * 256];   // 3 x 16 KB
    __shared__ __align__(16) float  cn_lds[KS];                // 8 KB

    const int tid  = threadIdx.x;
    const int w    = tid >> 6;
    const int lane = tid & 63;
    const int quad = lane >> 4;
    const int mcol = lane & 15;
    const int tokBase   = blockIdx.x * 256 + w * 64;   // wave's 64 tokens
    const int codeBase0 = blockIdx.y * KS;

    // ---- A fragments: A[m=mcol][k=quad*8+j], full D=256 in regs (128 regs)
    half8 afrag[4][8];
    #pragma unroll
    for (int rt = 0; rt < 4; rt++) {
        const float* xr = x + (size_t)(tokBase + rt * 16 + mcol) * DDIM + quad * 8;
        #pragma unroll
        for (int dk = 0; dk < 8; dk++)
            afrag[rt][dk] = ldcvt8(xr + dk * 32);
    }

    // ---- B-read LDS offsets: row = mcol, chunk = (dk*4+quad)^(mcol&7)
    int boff[8];
    #pragma unroll
    for (int dk = 0; dk < 8; dk++)
        boff[dk] = mcol * 256 + (((dk * 4 + quad) ^ (mcol & 7)) * 8);

    // packed top-2 keys (max semantics) per owned token [rt][r]
    float k0[4][4], k1[4][4];
    #pragma unroll
    for (int rt = 0; rt < 4; rt++)
        #pragma unroll
        for (int r = 0; r < 4; r++) { k0[rt][r] = -INFINITY; k1[rt][r] = -INFINITY; }

    // stage 16 KB tile nt into buffer slot si (async, swizzled to match
    // read side): 1024 x 16B chunks, 4/thread; dest chunk = o*256 + tid
    // (wave-uniform base + lane x 16 implicit in global_load_lds).
    const char*   cbbase  = (const char*)(cb16 + (size_t)codeBase0 * DDIM);
    half_t* const bufbase = &buf[0][0];
    #define STAGE(nt, si)                                                       \
        {                                                                       \
            const char* srcb = cbbase + (size_t)(nt) * (TCODES * 512);          \
            half_t* dstb = bufbase + (si) * (TCODES * 256);                     \
            _Pragma("unroll")                                                   \
            for (int o = 0; o < 4; o++) {                                       \
                int L = o * 256 + tid;                                          \
                int r = L >> 5, c = (L & 31) ^ (r & 7);                         \
                __builtin_amdgcn_global_load_lds(                               \
                    (const GLOBAL_AS void*)(srcb + r * 512 + c * 16),           \
                    (LDS_AS void*)(dstb + (o * 256 + w * 64) * 8), 16, 0, 0);   \
            }                                                                   \
        }

    // one-time cnorm slice -> LDS (8 x 4B per thread, drains with prologue)
    {
        const float* cnsrc = cnorm + codeBase0;
        #pragma unroll
        for (int o = 0; o < 8; o++)
            __builtin_amdgcn_global_load_lds(
                (const GLOBAL_AS void*)(cnsrc + o * 256 + w * 64 + lane),
                (LDS_AS void*)&cn_lds[o * 256 + w * 64], 4, 0, 0);
    }
    STAGE(0, 0)
    STAGE(1, 1)
    asm volatile("s_waitcnt vmcnt(0)" ::: "memory");   // prologue drain (only one)
    __builtin_amdgcn_s_barrier();

    int cc = 0;   // compute slot = nt % 3
    int sc = 2;   // stage slot   = (nt+2) % 3

    for (int nt = 0; nt < NSTEP; nt++) {
        // depth-2 prefetch: issue tile nt+2, wait so tile nt is resident.
        if (nt + 2 < NSTEP) {
            STAGE(nt + 2, sc)
            asm volatile("s_waitcnt vmcnt(8)" ::: "memory");
        } else if (nt + 1 < NSTEP) {
            asm volatile("s_waitcnt vmcnt(4)" ::: "memory");
        } else {
            asm volatile("s_waitcnt vmcnt(0)" ::: "memory");
        }
        __builtin_amdgcn_s_barrier();       // B1: tile nt resident for all waves

        const half_t* cur = bufbase + cc * (TCODES * 256);

        const float mc0 = -0.5f * cn_lds[nt * TCODES + mcol];
        const float mc1 = -0.5f * cn_lds[nt * TCODES + 16 + mcol];
        f32x4 acc[2][4];                    // [ct][rt]
        #pragma unroll
        for (int rt = 0; rt < 4; rt++) {
            acc[0][rt][0]=mc0; acc[0][rt][1]=mc0; acc[0][rt][2]=mc0; acc[0][rt][3]=mc0;
            acc[1][rt][0]=mc1; acc[1][rt][1]=mc1; acc[1][rt][2]=mc1; acc[1][rt][3]=mc1;
        }
        const half_t* crow0 = cur;
        const half_t* crow1 = cur + 16 * 256;
        __builtin_amdgcn_s_setprio(1);
        #pragma unroll
        for (int dk = 0; dk < 8; dk++) {
            half8 bf0 = *(const half8*)(crow0 + boff[dk]);
            half8 bf1 = *(const half8*)(crow1 + boff[dk]);
            #pragma unroll
            for (int rt = 0; rt < 4; rt++) {
                acc[0][rt] = __builtin_amdgcn_mfma_f32_16x16x32_f16(afrag[rt][dk], bf0, acc[0][rt], 0, 0, 0);
                acc[1][rt] = __builtin_amdgcn_mfma_f32_16x16x32_f16(afrag[rt][dk], bf1, acc[1][rt], 0, 0, 0);
            }
        }
        __builtin_amdgcn_s_setprio(0);
        // C layout: col = lane&15 (code), row = quad*4 + r (token).
        const unsigned code0 = (unsigned)(codeBase0 + nt * TCODES + mcol);
        const unsigned code1 = code0 + 16;
        #pragma unroll
        for (int rt = 0; rt < 4; rt++)
            #pragma unroll
            for (int r = 0; r < 4; r++) {
                float a = packkey(acc[0][rt][r], code0);
                float b = packkey(acc[1][rt][r], code1);
                k1[rt][r] = fmaxf(k1[rt][r], __builtin_amdgcn_fmed3f(k0[rt][r], a, b));
                k0[rt][r] = fmaxf(fmaxf(k0[rt][r], a), b);
            }
        __builtin_amdgcn_s_barrier();       // B2: reads of buf[cc] done ->
                                            // later STAGE may overwrite it
        cc = (cc == NBUF - 1) ? 0 : cc + 1;
        sc = (sc == NBUF - 1) ? 0 : sc + 1;
    }

    // ---- merge top-2 (max) across the 16 class lanes; lane mcol==0 writes.
    #pragma unroll
    for (int s = 1; s < 16; s <<= 1) {
        #pragma unroll
        for (int rt = 0; rt < 4; rt++)
            #pragma unroll
            for (int r = 0; r < 4; r++) {
                float o0 = __shfl_xor(k0[rt][r], s, 64);
                float o1 = __shfl_xor(k1[rt][r], s, 64);
                float n1 = fmaxf(fminf(k0[rt][r], o0), fmaxf(k1[rt][r], o1));
                k0[rt][r] = fmaxf(k0[rt][r], o0);
                k1[rt][r] = n1;
            }
    }
    if (mcol == 0) {
        #pragma unroll
        for (int rt = 0; rt < 4; rt++)
            #pragma unroll
            for (int r = 0; r < 4; r++) {
                int token = tokBase + rt * 16 + quad * 4 + r;
                f32x2 kk; kk[0] = k0[rt][r]; kk[1] = k1[rt][r];
                *(f32x2*)&cand[(size_t)token * (SLICES * 2) + blockIdx.y * 2] = kk;
            }
    }
}

// ---------------------------------------------------------------------------
// K2: 1 token/wave.  (R0 verbatim)
__global__ __launch_bounds__(256) void finalize_kernel(
    const float* __restrict__ x, const float* __restrict__ cb,
    const float* __restrict__ cnorm, const float* __restrict__ cand,
    float* __restrict__ out, float* __restrict__ partials) {

    const int tid = threadIdx.x, w = tid >> 6, lane = tid & 63;
    const int token = blockIdx.x * 4 + w;
    const float* xrow = x + (size_t)token * DDIM;

    f32x4 ka = *(const f32x4*)(cand + (size_t)token * 8);
    f32x4 kb = *(const f32x4*)(cand + (size_t)token * 8 + 4);
    float v[8] = {ka[0], ka[1], ka[2], ka[3], kb[0], kb[1], kb[2], kb[3]};
    float t0 = -INFINITY, t1 = -INFINITY;
    #pragma unroll
    for (int j = 0; j < 8; j++) {
        float m = fminf(t0, v[j]);
        t0 = fmaxf(t0, v[j]);
        t1 = fmaxf(t1, m);
    }
    int bidx = (int)(__float_as_uint(t0) & 0x1FFFu);

    if (!(t0 - t1 > MARGIN)) {
        const int j = lane >> 3, sub = lane & 7;
        int cj = (int)(__float_as_uint(v[j]) & 0x1FFFu);
        const float* crow = cb + (size_t)cj * DDIM;
        float p = 0.0f;
        #pragma unroll
        for (int c = 0; c < 8; c++) {
            f32x4 xa = *(const f32x4*)(xrow + c * 32 + sub * 4);
            f32x4 ca = *(const f32x4*)(crow + c * 32 + sub * 4);
            p += xa[0]*ca[0] + xa[1]*ca[1] + xa[2]*ca[2] + xa[3]*ca[3];
        }
        p += __shfl_xor(p, 1, 64);
        p += __shfl_xor(p, 2, 64);
        p += __shfl_xor(p, 4, 64);
        float bd = cnorm[cj] - 2.0f * p;
        int   bi = cj;
        #pragma unroll
        for (int s = 8; s < 64; s <<= 1) {   // reference tie-break: lower index
            float od = __shfl_xor(bd, s, 64);
            int   oi = __shfl_xor(bi, s, 64);
            if (od < bd || (od == bd && oi < bi)) { bd = od; bi = oi; }
        }
        bidx = bi;
    }

    f32x4 cv = *(const f32x4*)(cb + (size_t)bidx * DDIM + lane * 4);
    f32x4 xv = *(const f32x4*)(xrow + lane * 4);
    *(f32x4*)(out + (size_t)token * DDIM + lane * 4) = cv;
    float d0 = cv[0]-xv[0], d1 = cv[1]-xv[1], d2 = cv[2]-xv[2], d3 = cv[3]-xv[3];
    float lsum = d0*d0 + d1*d1 + d2*d2 + d3*d3;

    __shared__ float red[256];
    red[tid] = lsum;
    __syncthreads();
    #pragma unroll
    for (int s = 128; s > 0; s >>= 1) {
        if (tid < s) red[tid] += red[tid + s];
        __syncthreads();
    }
    if (tid == 0) partials[blockIdx.x] = red[0];
}

// ---------------------------------------------------------------------------
// K3: single-block sum of the 8192 per-block loss partials.  (R0 verbatim)
__global__ __launch_bounds__(256) void reduce_loss(const float* __restrict__ partials,
                                                   float* __restrict__ out) {
    const int tid = threadIdx.x;
    float s = 0.0f;
    #pragma unroll
    for (int i = 0; i < 8; i++) {
        f32x4 v = *(const f32x4*)(partials + (size_t)(i * 256 + tid) * 4);
        s += v[0] + v[1] + v[2] + v[3];
    }
    __shared__ float red[256];
    red[tid] = s;
    __syncthreads();
    #pragma unroll
    for (int st = 128; st > 0; st >>= 1) {
        if (tid < st) red[tid] += red[tid + st];
        __syncthreads();
    }
    if (tid == 0)
        out[(size_t)N_TOK * DDIM] = red[0] * (0.25f / (float)((size_t)N_TOK * DDIM));
}

// ---------------------------------------------------------------------------
extern "C" void kernel_launch(void* const* d_in, const int* in_sizes, int n_in,
                              void* d_out, int out_size, void* d_ws, size_t ws_size,
                              hipStream_t stream) {
    const float* x  = (const float*)d_in[0];
    const float* cb = (const float*)d_in[1];
    float* out = (float*)d_out;

    // ws: cb16 (4 MB f16) | cnorm[8192] | cand[32768*8] | partials[8192]
    half_t* cb16     = (half_t*)d_ws;
    float*  cnorm    = (float*)(cb16 + (size_t)KCB * DDIM);
    float*  cand     = cnorm + KCB;
    float*  partials = cand + (size_t)N_TOK * 8;

    prep_cb<<<KCB, 64, 0, stream>>>(cb, cb16, cnorm);
    dim3 gA(N_TOK / 256, SLICES);
    passA<<<gA, 256, 0, stream>>>(x, cb16, cnorm, cand);
    finalize_kernel<<<NFBLK, 256, 0, stream>>>(x, cb, cnorm, cand, out, partials);
    reduce_loss<<<1, 256, 0, stream>>>(partials, out);
}